// Round 1
// 258.350 us; speedup vs baseline: 1.0227x; 1.0227x over previous
//
#include <hip/hip_runtime.h>

typedef __attribute__((ext_vector_type(8))) short short8;
typedef __attribute__((ext_vector_type(4))) float f32x4;

#define XP_ELEMS (32u * 66u * 66u * 128u)  /* 17,842,176 bf16 elements */
#define WT_ELEMS (256u * 1152u)            /* 294,912 bf16 elements */
#define WS_NEED  ((size_t)(XP_ELEMS + WT_ELEMS) * 2u)

typedef const __attribute__((address_space(1))) void* gp1_t;
typedef __attribute__((address_space(3))) void* lp3_t;

__device__ __forceinline__ void gload16(const void* g, void* l) {
  __builtin_amdgcn_global_load_lds((gp1_t)g, (lp3_t)l, 16, 0, 0);
}

__device__ __forceinline__ short f2bf(float f) {
  unsigned u = __float_as_uint(f);
  u = (u + 0x7FFFu + ((u >> 16) & 1u)) >> 16;  // RNE truncate to bf16
  return (short)u;
}

// Transpose one (b, y) plane: x[b][cin][y][px] fp32 -> x_p[b][y+1][px+1][cin] bf16.
// Coalesced float4 reads, LDS round-trip (granule XOR swizzle), coalesced short8
// writes. Halo (px=0/65 cols; py=0/65 rows) zeroed here too.
__global__ __launch_bounds__(256) void prepass_x(const float* __restrict__ x,
                                                 short* __restrict__ xp) {
  __shared__ short lds[64 * 128];  // [px][cin, granule-swizzled], 16 KB
  const int y = blockIdx.x;   // 0..63
  const int b = blockIdx.y;   // 0..31
  const int t = threadIdx.x;

  const float* src = x + (long)b * 128 * 4096 + y * 64;
#pragma unroll
  for (int i = 0; i < 8; ++i) {
    int f4 = t + i * 256;          // 0..2047
    int cin = f4 >> 4, px4 = f4 & 15;
    float4 v = *(const float4*)(src + (long)cin * 4096 + px4 * 4);
    float vv[4] = {v.x, v.y, v.z, v.w};
#pragma unroll
    for (int j = 0; j < 4; ++j) {
      int px = px4 * 4 + j;
      int g = (cin >> 3) ^ ((px ^ (px >> 2)) & 15);
      lds[px * 128 + (g << 3) + (cin & 7)] = f2bf(vv[j]);
    }
  }
  __syncthreads();
  short* dst = xp + ((long)(b * 66 + y + 1) * 66 + 1) * 128;
#pragma unroll
  for (int i = 0; i < 4; ++i) {
    int f8 = t + i * 256;          // 0..1023
    int px = f8 >> 4, c8 = f8 & 15;
    int g = c8 ^ ((px ^ (px >> 2)) & 15);
    short8 v = *(const short8*)&lds[px * 128 + (g << 3)];
    *(short8*)(dst + (long)px * 128 + c8 * 8) = v;
  }
  // column halo px=0 / px=65 for this padded row
  short8 z = (short8)0;
  short* rowbase = xp + (long)(b * 66 + y + 1) * 66 * 128;
  if (t < 32) {
    int px = (t < 16) ? 0 : 65;
    int c8 = t & 15;
    *(short8*)(rowbase + (long)px * 128 + c8 * 8) = z;
  }
  if (y == 0) {
    short* r0 = xp + (long)(b * 66) * 66 * 128;
    for (int idx = t; idx < 66 * 16; idx += 256) *(short8*)(r0 + idx * 8) = z;
  }
  if (y == 63) {
    short* r65 = xp + ((long)(b * 66) + 65) * 66 * 128;
    for (int idx = t; idx < 66 * 16; idx += 256) *(short8*)(r65 + idx * 8) = z;
  }
}

// weight[cout][cin][kh][kw] fp32 -> w_t[cout][kh][kw][cin] bf16 (k=(kh*3+kw)*128+cin)
__global__ __launch_bounds__(256) void prepass_w(const float* __restrict__ w,
                                                 short* __restrict__ wt) {
  int o    = blockIdx.x * 256 + threadIdx.x;  // < 294912 exactly
  int cout = o / 1152;
  int r    = o % 1152;
  int kh   = r / 384;
  int kw   = (r / 128) % 3;
  int cin  = r & 127;
  wt[o] = f2bf(w[((cout * 128 + cin) * 3 + kh) * 3 + kw]);
}

// Implicit-GEMM conv, deep-pipelined:
//   C[m=cout 0..255][n=b*4096+y*64+x], tile 256x256, 8 waves (2M x 4N),
//   per-wave 128x64 output = acc[8][4] of 16x16x32 bf16 MFMA.
//   K = 1152 = 36 chunks of 32; 4-deep LDS ring (128 KiB), chunk c+3 staged
//   at start of compute(c); end-of-chunk sync = counted s_waitcnt vmcnt(8)
//   + raw s_barrier (never drains vmcnt in steady state).  Granule XOR
//   swizzle ((row>>1)&3) keeps ds_read_b128 conflict-free with lane-linear
//   global_load_lds destinations (swizzle applied to the global source).
__global__ __launch_bounds__(512, 2) void conv_gemm(const short* __restrict__ xp,
                                                    const short* __restrict__ wt,
                                                    float* __restrict__ out) {
  __shared__ alignas(16) short Al[4][256 * 32];  // 64 KB
  __shared__ alignas(16) short Bl[4][256 * 32];  // 64 KB
  const int tid = threadIdx.x;
  const int w   = tid >> 6;     // wave 0..7
  const int l   = tid & 63;
  const int l15 = l & 15;
  const int q   = l >> 4;
  const int wm2 = w >> 2;       // wave M half 0..1
  const int wn4 = w & 3;        // wave N quarter 0..3
  const int ntile = blockIdx.x; // 0..511 (n-tiles of 256; tile never spans images)

  // ---- staging source offsets: thread covers LDS slots tid and 512+tid.
  // slot s -> row r = s>>2, granule p = s&3; source k-subchunk = p ^ ((r>>1)&3).
  const int r0  = tid >> 2;        // 0..127
  const int r1  = r0 + 128;        // 128..255
  const int p0  = tid & 3;
  const int cs0 = p0 ^ ((r0 >> 1) & 3);
  const int cs1 = p0 ^ ((r1 >> 1) & 3);
  const long aoff0 = (long)r0 * 1152 + (cs0 << 3);
  const long aoff1 = (long)r1 * 1152 + (cs1 << 3);

  long boff0, boff1;
  {
    int n0 = (ntile << 8) + r0;
    int bb = n0 >> 12, yx = n0 & 4095, y = yx >> 6, xx = yx & 63;
    boff0 = ((long)(bb * 66 + y) * 66 + xx) * 128 + (cs0 << 3);
    int n1 = n0 + 128;
    bb = n1 >> 12; yx = n1 & 4095; y = yx >> 6; xx = yx & 63;
    boff1 = ((long)(bb * 66 + y) * 66 + xx) * 128 + (cs1 << 3);
  }
  const int ldst0 = tid * 8;          // LDS short-offset, slot 0
  const int ldst1 = (512 + tid) * 8;  // slot 1

  // ---- frag read offsets (chunk-invariant; proven conflict-free layout)
  int aRd[8], bRd[4];
#pragma unroll
  for (int mi = 0; mi < 8; ++mi) {
    int r = (wm2 << 7) + (mi << 4) + l15;
    aRd[mi] = r * 32 + ((q ^ ((r >> 1) & 3)) << 3);
  }
#pragma unroll
  for (int nj = 0; nj < 4; ++nj) {
    int r = (wn4 << 6) + (nj << 4) + l15;
    bRd[nj] = r * 32 + ((q ^ ((r >> 1) & 3)) << 3);
  }

  f32x4 acc[8][4];
#pragma unroll
  for (int mi = 0; mi < 8; ++mi)
#pragma unroll
    for (int nj = 0; nj < 4; ++nj) acc[mi][nj] = (f32x4)0.f;

  // stage one 32-k chunk (A: 256x32 of wt, B: 256x32 of shifted xp) -> 4 loads
  auto STAGE = [&](int kss, int bufS) {
    const int kq = kss >> 2;             // khkw 0..8
    const int kh = kq / 3, kw2 = kq % 3;
    const long sBs = (long)(kh * 66 + kw2) * 128 + ((kss & 3) << 5);
    const long ka  = (long)kss << 5;
    gload16(wt + aoff0 + ka, &Al[bufS][ldst0]);
    gload16(wt + aoff1 + ka, &Al[bufS][ldst1]);
    gload16(xp + boff0 + sBs, &Bl[bufS][ldst0]);
    gload16(xp + boff1 + sBs, &Bl[bufS][ldst1]);
  };

  // prologue: fill 3 of 4 ring slots; certify chunk 0 only (8 loads in flight)
  STAGE(0, 0); STAGE(1, 1); STAGE(2, 2);
  asm volatile("s_waitcnt vmcnt(8)" ::: "memory");
  __builtin_amdgcn_s_barrier();
  __builtin_amdgcn_sched_barrier(0);

#pragma unroll
  for (int ks = 0; ks < 36; ++ks) {
    if (ks + 3 < 36) STAGE(ks + 3, (ks + 3) & 3);

    const short* Ab = &Al[ks & 3][0];
    const short* Bb = &Bl[ks & 3][0];
    short8 af[8], bf[4];
#pragma unroll
    for (int mi = 0; mi < 8; ++mi) af[mi] = *(const short8*)&Ab[aRd[mi]];
#pragma unroll
    for (int nj = 0; nj < 4; ++nj) bf[nj] = *(const short8*)&Bb[bRd[nj]];

    __builtin_amdgcn_s_setprio(1);
#pragma unroll
    for (int mi = 0; mi < 8; ++mi)
#pragma unroll
      for (int nj = 0; nj < 4; ++nj)
        acc[mi][nj] = __builtin_amdgcn_mfma_f32_16x16x32_bf16(af[mi], bf[nj],
                                                              acc[mi][nj], 0, 0, 0);
    __builtin_amdgcn_s_setprio(0);

    if (ks + 1 < 36) {
      // certify chunk ks+1 block-wide; keep later chunks' loads in flight.
      if (ks + 3 < 36)      asm volatile("s_waitcnt vmcnt(8)" ::: "memory");
      else if (ks + 2 < 36) asm volatile("s_waitcnt vmcnt(4)" ::: "memory");
      else                  asm volatile("s_waitcnt vmcnt(0)" ::: "memory");
      __builtin_amdgcn_s_barrier();
      __builtin_amdgcn_sched_barrier(0);
    }
  }

  // epilogue: C/D layout col=lane&15, row=quad*4+reg (m89/m91-verified)
  const int bimg = ntile >> 4;
  const int yx0  = ((ntile & 15) << 8) + (wn4 << 6) + l15;
  float* outb = out + (long)bimg * (256 * 4096) + yx0;
#pragma unroll
  for (int mi = 0; mi < 8; ++mi) {
#pragma unroll
    for (int r = 0; r < 4; ++r) {
      const int cout = (wm2 << 7) + (mi << 4) + (q << 2) + r;
      float* orow = outb + (long)cout * 4096;
#pragma unroll
      for (int nj = 0; nj < 4; ++nj) orow[nj << 4] = acc[mi][nj][r];
    }
  }
}

// Correctness fallback if workspace is too small (slow, fp32 direct conv).
__global__ __launch_bounds__(256) void naive_conv(const float* __restrict__ x,
                                                  const float* __restrict__ wgt,
                                                  float* __restrict__ out) {
  long o = (long)blockIdx.x * 256 + threadIdx.x;
  int xx = (int)(o & 63);
  int y  = (int)((o >> 6) & 63);
  int co = (int)((o >> 12) & 255);
  int b  = (int)(o >> 20);
  float s = 0.f;
  for (int ci = 0; ci < 128; ++ci) {
    for (int kh = 0; kh < 3; ++kh) {
      int iy = y + kh - 1;
      if (iy < 0 || iy > 63) continue;
      for (int kw = 0; kw < 3; ++kw) {
        int ix = xx + kw - 1;
        if (ix < 0 || ix > 63) continue;
        s += x[((long)(b * 128 + ci) * 64 + iy) * 64 + ix] *
             wgt[((co * 128 + ci) * 3 + kh) * 3 + kw];
      }
    }
  }
  out[o] = s;
}

extern "C" void kernel_launch(void* const* d_in, const int* in_sizes, int n_in,
                              void* d_out, int out_size, void* d_ws, size_t ws_size,
                              hipStream_t stream) {
  (void)in_sizes; (void)n_in;
  const float* x   = (const float*)d_in[0];
  const float* wgt = (const float*)d_in[1];
  float* out = (float*)d_out;
  if (ws_size >= WS_NEED) {
    short* xp = (short*)d_ws;
    short* wt = xp + XP_ELEMS;
    prepass_x<<<dim3(64, 32), dim3(256), 0, stream>>>(x, xp);
    prepass_w<<<dim3(WT_ELEMS / 256), dim3(256), 0, stream>>>(wgt, wt);
    conv_gemm<<<dim3(512), dim3(512), 0, stream>>>(xp, wt, out);
  } else {
    naive_conv<<<dim3(out_size / 256), dim3(256), 0, stream>>>(x, wgt, out);
  }
}

// Round 2
// 254.439 us; speedup vs baseline: 1.0384x; 1.0154x over previous
//
#include <hip/hip_runtime.h>

typedef __attribute__((ext_vector_type(8))) short short8;
typedef __attribute__((ext_vector_type(4))) float f32x4;

#define XP_ELEMS (32u * 66u * 66u * 128u)  /* 17,842,176 bf16 elements */
#define WT_ELEMS (256u * 1152u)            /* 294,912 bf16 elements */
#define WS_NEED  ((size_t)(XP_ELEMS + WT_ELEMS) * 2u)

typedef const __attribute__((address_space(1))) void* gp1_t;
typedef __attribute__((address_space(3))) void* lp3_t;

__device__ __forceinline__ void gload16(const void* g, void* l) {
  __builtin_amdgcn_global_load_lds((gp1_t)g, (lp3_t)l, 16, 0, 0);
}

__device__ __forceinline__ short f2bf(float f) {
  unsigned u = __float_as_uint(f);
  u = (u + 0x7FFFu + ((u >> 16) & 1u)) >> 16;  // RNE truncate to bf16
  return (short)u;
}

// Transpose one (b, y) plane: x[b][cin][y][px] fp32 -> x_p[b][y+1][px+1][cin] bf16.
__global__ __launch_bounds__(256) void prepass_x(const float* __restrict__ x,
                                                 short* __restrict__ xp) {
  __shared__ short lds[64 * 128];  // [px][cin, granule-swizzled], 16 KB
  const int y = blockIdx.x;   // 0..63
  const int b = blockIdx.y;   // 0..31
  const int t = threadIdx.x;

  const float* src = x + (long)b * 128 * 4096 + y * 64;
#pragma unroll
  for (int i = 0; i < 8; ++i) {
    int f4 = t + i * 256;          // 0..2047
    int cin = f4 >> 4, px4 = f4 & 15;
    float4 v = *(const float4*)(src + (long)cin * 4096 + px4 * 4);
    float vv[4] = {v.x, v.y, v.z, v.w};
#pragma unroll
    for (int j = 0; j < 4; ++j) {
      int px = px4 * 4 + j;
      int g = (cin >> 3) ^ ((px ^ (px >> 2)) & 15);
      lds[px * 128 + (g << 3) + (cin & 7)] = f2bf(vv[j]);
    }
  }
  __syncthreads();
  short* dst = xp + ((long)(b * 66 + y + 1) * 66 + 1) * 128;
#pragma unroll
  for (int i = 0; i < 4; ++i) {
    int f8 = t + i * 256;          // 0..1023
    int px = f8 >> 4, c8 = f8 & 15;
    int g = c8 ^ ((px ^ (px >> 2)) & 15);
    short8 v = *(const short8*)&lds[px * 128 + (g << 3)];
    *(short8*)(dst + (long)px * 128 + c8 * 8) = v;
  }
  short8 z = (short8)0;
  short* rowbase = xp + (long)(b * 66 + y + 1) * 66 * 128;
  if (t < 32) {
    int px = (t < 16) ? 0 : 65;
    int c8 = t & 15;
    *(short8*)(rowbase + (long)px * 128 + c8 * 8) = z;
  }
  if (y == 0) {
    short* r0 = xp + (long)(b * 66) * 66 * 128;
    for (int idx = t; idx < 66 * 16; idx += 256) *(short8*)(r0 + idx * 8) = z;
  }
  if (y == 63) {
    short* r65 = xp + ((long)(b * 66) + 65) * 66 * 128;
    for (int idx = t; idx < 66 * 16; idx += 256) *(short8*)(r65 + idx * 8) = z;
  }
}

// weight[cout][cin][kh][kw] fp32 -> w_t[cout][kh][kw][cin] bf16
__global__ __launch_bounds__(256) void prepass_w(const float* __restrict__ w,
                                                 short* __restrict__ wt) {
  int o    = blockIdx.x * 256 + threadIdx.x;  // < 294912 exactly
  int cout = o / 1152;
  int r    = o % 1152;
  int kh   = r / 384;
  int kw   = (r / 128) % 3;
  int cin  = r & 127;
  wt[o] = f2bf(w[((cout * 128 + cin) * 3 + kh) * 3 + kw]);
}

// Implicit-GEMM conv, m201-style 8-phase schedule:
//   C[m=cout 0..255][n], tile 256x256, 8 waves (2M x 4N), per-wave 128x64
//   = acc[8][4] of 16x16x32 bf16 MFMA.  K = 1152 = 18 K-tiles of 64
//   (K-tile T: khkw=T>>1, cin-half=T&1); slot = T&1, 9 iterations of 2 K-tiles.
//   Per K-tile: 4 quadrant phases (mq,nq)=(0,0),(0,1),(1,0),(1,1);
//   per phase: {new frag ds_reads (12/4/8/0), 1 staging unit (2 gload_lds),
//   barrier, lgkmcnt(0), setprio, 16 MFMA, [vmcnt(4) at P3/P7], barrier}.
//   Staging units (8 KB, 2 loads/phase): issue slot is one phase after the
//   last LDS read of the region overwritten; consumption certified by the
//   counted vmcnt(4) fences (never drains in steady state).
//   LDS [slot][h][c][row 128][32 shorts] with k-granule XOR swizzle
//   ((row>>1)&3): ds_read_b128 conflict-free, gload_lds dests lane-linear.
__global__ __launch_bounds__(512, 2) void conv_gemm(const short* __restrict__ xp,
                                                    const short* __restrict__ wt,
                                                    float* __restrict__ out) {
  __shared__ alignas(16) short Alds[2 * 2 * 2 * 128 * 32];  // 64 KB
  __shared__ alignas(16) short Blds[2 * 2 * 2 * 128 * 32];  // 64 KB
  const int tid = threadIdx.x;
  const int w   = tid >> 6;     // wave 0..7
  const int l   = tid & 63;
  const int l15 = l & 15;
  const int q   = l >> 4;
  const int wm2 = w >> 2;       // wave M half 0..1
  const int wn4 = w & 3;        // wave N quarter 0..3
  const int ntile = blockIdx.x; // 0..511

  // ---- staging thread decomposition: t -> (chunk cc, row r6, granule pp)
  const int r6 = (tid >> 2) & 63;
  const int cc = tid >> 8;
  const int pp = tid & 3;
  const int cs = pp ^ ((r6 >> 1) & 3);              // source k-granule (swizzle)
  const int aTh  = r6 * 1152 + cc * 32 + cs * 8;    // A per-thread src offset
  const int ldsA = cc * 4096 + r6 * 32 + pp * 8;    // per-thread LDS dest
  const int ldsB0 = ldsA + ((r6 & 32) << 5);        // B unit n0: rows {0-31,64-95}
  int bTh[2][2];                                    // [hb][nq] per-thread B src
#pragma unroll
  for (int hb = 0; hb < 2; ++hb)
#pragma unroll
    for (int nq = 0; nq < 2; ++nq) {
      int R  = (r6 & 31) + ((r6 >> 5) << 6) + nq * 32;  // LDS row within half
      int n  = (ntile << 8) + (hb << 7) + R;
      int bb = n >> 12, yy = (n >> 6) & 63, xx = n & 63;
      bTh[hb][nq] = ((bb * 66 + yy) * 66 + xx) * 128 + cc * 32 + cs * 8;
    }

  // ---- frag read offsets (chunk-invariant, conflict-free)
  int aRd[8], bRd[4];
#pragma unroll
  for (int mi = 0; mi < 8; ++mi) {
    int r = (mi << 4) + l15;
    aRd[mi] = r * 32 + ((q ^ ((r >> 1) & 3)) << 3);
  }
#pragma unroll
  for (int nj = 0; nj < 4; ++nj) {
    int r = ((wn4 & 1) << 6) + (nj << 4) + l15;
    bRd[nj] = r * 32 + ((q ^ ((r >> 1) & 3)) << 3);
  }
  const int aHB = wm2 * 8192;        // wave's A half base (within slot)
  const int bHB = (wn4 >> 1) * 8192; // wave's B half base

  f32x4 acc[8][4];
#pragma unroll
  for (int mi = 0; mi < 8; ++mi)
#pragma unroll
    for (int nj = 0; nj < 4; ++nj) acc[mi][nj] = (f32x4)0.f;

  short8 af[4][2], bf[4][2];

  // ---- staging units: 2 gload_lds each (both h), 8 KB/unit
  auto ST_A = [&](int s, int v, int kb) {
    gload16(wt + kb + v * 73728 + aTh,
            &Alds[s * 16384 + v * 2048 + ldsA]);
    gload16(wt + kb + 147456 + v * 73728 + aTh,
            &Alds[s * 16384 + 8192 + v * 2048 + ldsA]);
  };
  auto ST_B = [&](int s, int nq, int sh) {
    gload16(xp + sh + bTh[0][nq], &Blds[s * 16384 + (nq << 10) + ldsB0]);
    gload16(xp + sh + bTh[1][nq], &Blds[s * 16384 + 8192 + (nq << 10) + ldsB0]);
  };
  auto LD_A = [&](int s, int mq) {
#pragma unroll
    for (int i = 0; i < 4; ++i)
#pragma unroll
      for (int c = 0; c < 2; ++c)
        af[i][c] = *(const short8*)&Alds[s * 16384 + aHB + c * 4096 + aRd[mq * 4 + i]];
  };
  auto LD_B = [&](int s, int nq) {
#pragma unroll
    for (int j = 0; j < 2; ++j)
#pragma unroll
      for (int c = 0; c < 2; ++c)
        bf[nq * 2 + j][c] =
            *(const short8*)&Blds[s * 16384 + bHB + c * 4096 + bRd[nq * 2 + j]];
  };
  auto MM = [&](int mq, int nq) {
    __builtin_amdgcn_s_setprio(1);
#pragma unroll
    for (int c = 0; c < 2; ++c)
#pragma unroll
      for (int i = 0; i < 4; ++i)
#pragma unroll
        for (int j = 0; j < 2; ++j)
          acc[mq * 4 + i][nq * 2 + j] = __builtin_amdgcn_mfma_f32_16x16x32_bf16(
              af[i][c], bf[nq * 2 + j][c], acc[mq * 4 + i][nq * 2 + j], 0, 0, 0);
    __builtin_amdgcn_s_setprio(0);
  };

#define BAR()   __builtin_amdgcn_s_barrier()
#define SBAR()  __builtin_amdgcn_sched_barrier(0)
#define LGKM0() do { asm volatile("s_waitcnt lgkmcnt(0)" ::: "memory"); SBAR(); } while (0)
#define VMC(n)  asm volatile("s_waitcnt vmcnt(" #n ")" ::: "memory")

  // ---- prologue: T0 (slot0) all 4 units + T1 (slot1) Av0, Bn0
  ST_A(0, 0, 0);  ST_B(0, 0, 0);     // T0.Av0, T0.Bn0   (khkw=0, cin-half 0)
  ST_A(0, 1, 0);  ST_B(0, 1, 0);     // T0.Av1, T0.Bn1
  ST_A(1, 0, 64); ST_B(1, 0, 64);    // T1.Av0, T1.Bn0   (cin-half 1)
  VMC(4);  // certify T0 (8 loads); T1's 4 remain in flight
  BAR(); SBAR();

#pragma unroll
  for (int J = 0; J < 9; ++J) {
    const int kh  = J / 3,        kw  = J % 3;
    const int khn = (J + 1) / 3,  kwn = (J + 1) % 3;
    const int kb1 = J * 128 + 64;           // A kbase, tile 2J+1
    const int kb2 = (J + 1) * 128;          // A kbase, tiles 2J+2 / 2J+3 (+64)
    const int sh1 = (kh * 66 + kw) * 128 + 64;    // B shift, tile 2J+1
    const int sh2 = (khn * 66 + kwn) * 128;       // B shift, tile 2J+2
    const int sh3 = sh2 + 64;                     // B shift, tile 2J+3

    // P0: T0 quad(0,0); stage slot1.Av1 (tile 2J+1)
    LD_A(0, 0); LD_B(0, 0);
    ST_A(1, 1, kb1);
    asm volatile("s_waitcnt lgkmcnt(8)" ::: "memory");
    BAR(); LGKM0(); MM(0, 0); BAR(); SBAR();

    // P1: T0 quad(0,1); stage slot1.Bn1 (tile 2J+1)
    LD_B(0, 1);
    ST_B(1, 1, sh1);
    BAR(); LGKM0(); MM(0, 1); BAR(); SBAR();

    // P2: T0 quad(1,0); stage slot0.Av0 (tile 2J+2)
    LD_A(0, 1);
    if (J < 8) ST_A(0, 0, kb2);
    BAR(); LGKM0(); MM(1, 0); BAR(); SBAR();

    // P3: T0 quad(1,1); stage slot0.Bn0; fence certifies tile 2J+1
    if (J < 8) ST_B(0, 0, sh2);
    BAR(); LGKM0(); MM(1, 1);
    if (J < 8) { VMC(4); } else { VMC(0); }
    BAR(); SBAR();

    // P4: T1 quad(0,0); stage slot0.Av1 (tile 2J+2)
    LD_A(1, 0); LD_B(1, 0);
    if (J < 8) ST_A(0, 1, kb2);
    asm volatile("s_waitcnt lgkmcnt(8)" ::: "memory");
    BAR(); LGKM0(); MM(0, 0); BAR(); SBAR();

    // P5: T1 quad(0,1); stage slot0.Bn1 (tile 2J+2)
    LD_B(1, 1);
    if (J < 8) ST_B(0, 1, sh2);
    BAR(); LGKM0(); MM(0, 1); BAR(); SBAR();

    // P6: T1 quad(1,0); stage slot1.Av0 (tile 2J+3)
    LD_A(1, 1);
    if (J < 8) ST_A(1, 0, kb2 + 64);
    BAR(); LGKM0(); MM(1, 0); BAR(); SBAR();

    // P7: T1 quad(1,1); stage slot1.Bn0 (tile 2J+3); fence certifies tile 2J+2
    if (J < 8) ST_B(1, 0, sh3);
    BAR(); LGKM0(); MM(1, 1);
    if (J < 8) { VMC(4); BAR(); SBAR(); }
  }

  // epilogue: C/D layout col=lane&15, row=quad*4+reg (m89/m91-verified)
  const int bimg = ntile >> 4;
  const int yx0  = ((ntile & 15) << 8) + (wn4 << 6) + l15;
  float* outb = out + (long)bimg * (256 * 4096) + yx0;
#pragma unroll
  for (int mi = 0; mi < 8; ++mi) {
#pragma unroll
    for (int r = 0; r < 4; ++r) {
      const int cout = (wm2 << 7) + (mi << 4) + (q << 2) + r;
      float* orow = outb + (long)cout * 4096;
#pragma unroll
      for (int nj = 0; nj < 4; ++nj) orow[nj << 4] = acc[mi][nj][r];
    }
  }
#undef BAR
#undef SBAR
#undef LGKM0
#undef VMC
}

// Correctness fallback if workspace is too small (slow, fp32 direct conv).
__global__ __launch_bounds__(256) void naive_conv(const float* __restrict__ x,
                                                  const float* __restrict__ wgt,
                                                  float* __restrict__ out) {
  long o = (long)blockIdx.x * 256 + threadIdx.x;
  int xx = (int)(o & 63);
  int y  = (int)((o >> 6) & 63);
  int co = (int)((o >> 12) & 255);
  int b  = (int)(o >> 20);
  float s = 0.f;
  for (int ci = 0; ci < 128; ++ci) {
    for (int kh = 0; kh < 3; ++kh) {
      int iy = y + kh - 1;
      if (iy < 0 || iy > 63) continue;
      for (int kw = 0; kw < 3; ++kw) {
        int ix = xx + kw - 1;
        if (ix < 0 || ix > 63) continue;
        s += x[((long)(b * 128 + ci) * 64 + iy) * 64 + ix] *
             wgt[((co * 128 + ci) * 3 + kh) * 3 + kw];
      }
    }
  }
  out[o] = s;
}

extern "C" void kernel_launch(void* const* d_in, const int* in_sizes, int n_in,
                              void* d_out, int out_size, void* d_ws, size_t ws_size,
                              hipStream_t stream) {
  (void)in_sizes; (void)n_in;
  const float* x   = (const float*)d_in[0];
  const float* wgt = (const float*)d_in[1];
  float* out = (float*)d_out;
  if (ws_size >= WS_NEED) {
    short* xp = (short*)d_ws;
    short* wt = xp + XP_ELEMS;
    prepass_x<<<dim3(64, 32), dim3(256), 0, stream>>>(x, xp);
    prepass_w<<<dim3(WT_ELEMS / 256), dim3(256), 0, stream>>>(wgt, wt);
    conv_gemm<<<dim3(512), dim3(512), 0, stream>>>(xp, wt, out);
  } else {
    naive_conv<<<dim3(out_size / 256), dim3(256), 0, stream>>>(x, wgt, out);
  }
}